// Round 12
// baseline (180.155 us; speedup 1.0000x reference)
//
#include <hip/hip_runtime.h>
#include <hip/hip_fp16.h>
#include <math.h>

#define N_NODES 10000
#define E_EDGES 160000
#define DMODEL 64
#define H 4
#define NBOUND 31
#define SLOTS 64  // fixed per-node CSR bucket; P(deg>64)<1e-11 for multinomial(16)
// qall record per node (fp16, 1024 halves):
//  [0:512)    interleaved h|q1 per lane-slot g = head*16+c (g in [0,64)):
//             halves g*8+0..3 = h[head][c*4..+3]
//             halves g*8+4..7 = q1[head][c*4..+3]
//             -> score+agg src-row gather is ONE uint4 per lane
//  [512:768)  q2: 512 + head*64 + d   (head-major)
//  [768:1024) q3: 768 + head*64 + d
#define QREC 1024

typedef _Float16 half8 __attribute__((ext_vector_type(8)));
typedef float floatx4 __attribute__((ext_vector_type(4)));

// ---------------------------------------------------------------------------
// LDS 64-wide microtile helper: o[r] = sum_t A[i0+r][t] * B[t][j].
// ---------------------------------------------------------------------------
__device__ __forceinline__ void mm4(const float* __restrict__ S, int aoff,
                                    int astride, int boff, int i0, int j,
                                    int Kdim, float o[4]) {
  float a0 = 0.f, a1 = 0.f, a2 = 0.f, a3 = 0.f;
  for (int t4 = 0; t4 < (Kdim >> 2); ++t4) {
    float4 f0 = *(const float4*)&S[aoff + (i0 + 0) * astride + t4 * 4];
    float4 f1 = *(const float4*)&S[aoff + (i0 + 1) * astride + t4 * 4];
    float4 f2 = *(const float4*)&S[aoff + (i0 + 2) * astride + t4 * 4];
    float4 f3 = *(const float4*)&S[aoff + (i0 + 3) * astride + t4 * 4];
    float b0 = S[boff + (t4 * 4 + 0) * 64 + j];
    float b1 = S[boff + (t4 * 4 + 1) * 64 + j];
    float b2 = S[boff + (t4 * 4 + 2) * 64 + j];
    float b3 = S[boff + (t4 * 4 + 3) * 64 + j];
    a0 += f0.x * b0 + f0.y * b1 + f0.z * b2 + f0.w * b3;
    a1 += f1.x * b0 + f1.y * b1 + f1.z * b2 + f1.w * b3;
    a2 += f2.x * b0 + f2.y * b1 + f2.z * b2 + f2.w * b3;
    a3 += f3.x * b0 + f3.y * b1 + f3.z * b2 + f3.w * b3;
  }
  o[0] = a0; o[1] = a1; o[2] = a2; o[3] = a3;
}

// Variant with the A-operand read straight from global (small L2-resident
// weight matrices; used by chain B so its LDS footprint stays at 16 KB).
__device__ __forceinline__ void mm4g(const float* __restrict__ A, int astride,
                                     const float* __restrict__ S, int boff,
                                     int i0, int j, int Kdim, float o[4]) {
  float a0 = 0.f, a1 = 0.f, a2 = 0.f, a3 = 0.f;
  for (int t4 = 0; t4 < (Kdim >> 2); ++t4) {
    float4 f0 = *(const float4*)&A[(i0 + 0) * astride + t4 * 4];
    float4 f1 = *(const float4*)&A[(i0 + 1) * astride + t4 * 4];
    float4 f2 = *(const float4*)&A[(i0 + 2) * astride + t4 * 4];
    float4 f3 = *(const float4*)&A[(i0 + 3) * astride + t4 * 4];
    float b0 = S[boff + (t4 * 4 + 0) * 64 + j];
    float b1 = S[boff + (t4 * 4 + 1) * 64 + j];
    float b2 = S[boff + (t4 * 4 + 2) * 64 + j];
    float b3 = S[boff + (t4 * 4 + 3) * 64 + j];
    a0 += f0.x * b0 + f0.y * b1 + f0.z * b2 + f0.w * b3;
    a1 += f1.x * b0 + f1.y * b1 + f1.z * b2 + f1.w * b3;
    a2 += f2.x * b0 + f2.y * b1 + f2.z * b2 + f2.w * b3;
    a3 += f3.x * b0 + f3.y * b1 + f3.z * b2 + f3.w * b3;
  }
  o[0] = a0; o[1] = a1; o[2] = a2; o[3] = a3;
}

__device__ __forceinline__ int didx(const float* __restrict__ bnd2, float d) {
  int g = (int)(d * 10.0f);
  g = (g < 0) ? 0 : ((g > 31) ? 31 : g);
  g += (bnd2[g + 1] < d) ? 1 : 0;
  g -= (bnd2[g] >= d) ? 1 : 0;
  return g;
}

// ---------------------------------------------------------------------------
// D1: prep (chain A only + util). Chain B lives in the fused kernel.
//   blocks  0..11 chain A0: B1 = fckU@F -> WC0 (+ raw WfcT upper, k==0)
//   blocks 12..23 chain A1: B1 = fckU@F -> WC1 (+ raw WfcT lower, k==0)
//   blocks 24..43: zero cnt + build pos4 table.
// ---------------------------------------------------------------------------
__global__ __launch_bounds__(512) void prep_kernel(
    const float* __restrict__ fc1, const float* __restrict__ fc2,
    const float* __restrict__ fc3, const float* __restrict__ fcc,
    const float* __restrict__ Wfc, const float* __restrict__ pos,
    __half* __restrict__ bigWT, int* __restrict__ cnt,
    float4* __restrict__ pos4) {
  __shared__ __align__(16) float S[12288];
  int bi = blockIdx.x;
  int tid = threadIdx.x;
  if (bi >= 24) {
    int n = (bi - 24) * 512 + tid;
    if (n < N_NODES) {
      cnt[n] = 0;
      pos4[n] = make_float4(pos[n * 3], pos[n * 3 + 1], pos[n * 3 + 2], 0.f);
    }
    return;
  }
  int ca = bi / 12;  // 0 = A0, 1 = A1
  int kh = bi % 12;
  int k = kh >> 2, h = kh & 3;
  const float* fck = (k == 0) ? fc1 : (k == 1) ? fc2 : fc3;
  fck += h * 128 * 64;
  const float* F = fcc + h * 192 * 64 + k * 64 * 64;
  int j = tid & 63, ig = tid >> 6;  // ig 0..7
  float o[4];
  // stage F -> S[0:4096), fckU -> S[4096:8192)
  #pragma unroll
  for (int u = 0; u < 2; ++u) {
    ((float4*)S)[u * 512 + tid] = ((const float4*)F)[u * 512 + tid];
    ((float4*)(S + 4096))[u * 512 + tid] = ((const float4*)fck)[u * 512 + tid];
  }
  __syncthreads();
  // B1 = fckU @ F -> S[8192)
  #pragma unroll
  for (int rg = 0; rg < 2; ++rg) {
    int i0 = ig * 8 + rg * 4;
    mm4(S, 4096, 64, 0, i0, j, 64, o);
    S[8192 + (i0 + 0) * 64 + j] = o[0];
    S[8192 + (i0 + 1) * 64 + j] = o[1];
    S[8192 + (i0 + 2) * 64 + j] = o[2];
    S[8192 + (i0 + 3) * 64 + j] = o[3];
  }
  __syncthreads();
  // stage Wfc rows (A0: 0..63, A1: 64..127), col slice h -> S[4096)
  int rbase = (ca == 0) ? 0 : 64;
  #pragma unroll
  for (int u = 0; u < 2; ++u) {
    int fi = u * 512 + tid;
    int i = fi >> 4, c4 = fi & 15;
    ((float4*)(S + 4096))[fi] =
        ((const float4*)(Wfc + (rbase + i) * 256 + h * 64))[c4];
  }
  __syncthreads();
  if (k == 0) {
    #pragma unroll
    for (int u = 0; u < 8; ++u) {
      int idx = u * 512 + tid;
      int i = idx >> 6, jj = idx & 63;
      bigWT[(h * 64 + jj) * 128 + rbase + i] = __float2half(S[4096 + idx]);
    }
  }
  // WC = Wfc-half @ B1 -> bigWT cols rbase..rbase+63
  #pragma unroll
  for (int rg = 0; rg < 2; ++rg) {
    int i0 = ig * 8 + rg * 4;
    mm4(S, 4096, 64, 8192, i0, j, 64, o);
    int rb = ((k + 1) * 256 + h * 64 + j) * 128 + rbase;
    bigWT[rb + i0 + 0] = __float2half(o[0]);
    bigWT[rb + i0 + 1] = __float2half(o[1]);
    bigWT[rb + i0 + 2] = __float2half(o[2]);
    bigWT[rb + i0 + 3] = __float2half(o[3]);
  }
}

// ---------------------------------------------------------------------------
// D2: FUSED chainB + gemm + edge, one dispatch, 256 threads. LDS union is
// now 16.6 KB (chain B stages only F; fckL/G/emb A-operands read from
// global via mm4g) -> 8 blocks/CU (wave-capped), 1.6x the r11 occupancy.
//   blocks 0..11      = chain B: B2 -> GB -> U -> U16
//   blocks 12..1261   = MFMA gemm: 16 rows x 512 cols per block (625/half).
//                       half 0 (h|q1) -> interleaved qall[0:512) via LDS
//                       permute + contiguous uint4 stores; half 1 (q2|q3)
//                       head-major. N = 625*16 exactly.
//   blocks 1262..1886 = edge pass (pos4 gathers, early atomic, CSR scatter)
// record uint4: x = s | it0<<16 ; y = it1 | it2<<16 ;
//               z = it3 | i1<<16 | q2_0<<21 | q__0<<26 ;
//               w = (q2_h | q__h<<5) << ((h-1)*10)  for h=1..3
// ---------------------------------------------------------------------------
#define EROW2 520  // epilogue LDS row stride in halves
#define SMEM_BYTES 16640  // Esm 16x520x2 = 16640; chainB F = 16384; Sb = 192

__global__ __launch_bounds__(256) void fused_kernel(
    const float* __restrict__ feat, const __half* __restrict__ bigWT,
    __half* __restrict__ qall, const float4* __restrict__ pos4,
    const int* __restrict__ src, const int* __restrict__ dst,
    const int* __restrict__ inter, const float* __restrict__ boundaries,
    int* __restrict__ cnt, uint4* __restrict__ ebuf,
    const float* __restrict__ fc1, const float* __restrict__ fc2,
    const float* __restrict__ fc3, const float* __restrict__ fcc,
    const float* __restrict__ G, const float* __restrict__ emb,
    __half* __restrict__ U16) {
  __shared__ __align__(16) char smem[SMEM_BYTES];
  int bi = blockIdx.x;
  int tid = threadIdx.x;
  if (bi < 12) {
    // ---- chain B: B2 -> GB -> U (F-only LDS staging, 16 KB) ----
    float* S = (float*)smem;  // 4096 floats = 16 KB
    int k = bi >> 2, h = bi & 3;
    const float* fck = (k == 0) ? fc1 : (k == 1) ? fc2 : fc3;
    fck += h * 128 * 64;
    const float* F = fcc + h * 192 * 64 + k * 64 * 64;
    int j = tid & 63, ig = tid >> 6;  // ig 0..3
    // stage F -> [0:4096)
    #pragma unroll
    for (int u = 0; u < 4; ++u)
      ((float4*)S)[u * 256 + tid] = ((const float4*)F)[u * 256 + tid];
    __syncthreads();
    // B2 = fckL @ F -> registers (A = fckL rows 64..127, global)
    float ob[4][4];
    #pragma unroll
    for (int rg = 0; rg < 4; ++rg)
      mm4g(fck + 4096, 64, S, 0, ig * 16 + rg * 4, j, 64, ob[rg]);
    __syncthreads();
    // write B2 -> [0:4096) (overwrites F)
    #pragma unroll
    for (int rg = 0; rg < 4; ++rg) {
      int i0 = ig * 16 + rg * 4;
      S[(i0 + 0) * 64 + j] = ob[rg][0];
      S[(i0 + 1) * 64 + j] = ob[rg][1];
      S[(i0 + 2) * 64 + j] = ob[rg][2];
      S[(i0 + 3) * 64 + j] = ob[rg][3];
    }
    __syncthreads();
    // GB = G @ B2 -> registers (A = G_h, global)
    float og[2][4];
    #pragma unroll
    for (int rg = 0; rg < 2; ++rg)
      mm4g(G + h * 2048, 64, S, 0, ig * 8 + rg * 4, j, 64, og[rg]);
    __syncthreads();
    // write GB -> [0:2048) (overwrites B2)
    #pragma unroll
    for (int rg = 0; rg < 2; ++rg) {
      int i0 = ig * 8 + rg * 4;
      S[(i0 + 0) * 64 + j] = og[rg][0];
      S[(i0 + 1) * 64 + j] = og[rg][1];
      S[(i0 + 2) * 64 + j] = og[rg][2];
      S[(i0 + 3) * 64 + j] = og[rg][3];
    }
    __syncthreads();
    // U = emb @ GB (K=32; A = emb 32x32, global) -> U16
    float o[4];
    #pragma unroll
    for (int rg = 0; rg < 2; ++rg) {
      int i0 = ig * 8 + rg * 4;
      mm4g(emb, 32, S, 0, i0, j, 32, o);
      int base = k * 8192 + h * 2048;
      U16[base + (i0 + 0) * 64 + j] = __float2half(o[0]);
      U16[base + (i0 + 1) * 64 + j] = __float2half(o[1]);
      U16[base + (i0 + 2) * 64 + j] = __float2half(o[2]);
      U16[base + (i0 + 3) * 64 + j] = __float2half(o[3]);
    }
    return;
  }
  if (bi >= 1262) {
    // ---- edge path ----
    float* Sb = (float*)smem;
    if (tid < NBOUND) Sb[tid + 1] = boundaries[tid];
    if (tid == NBOUND) { Sb[0] = -INFINITY; Sb[32] = INFINITY; }
    int e = (bi - 1262) * 256 + tid;  // 625*256 == E exactly
    int s = src[e], t = dst[e];
    int p = atomicAdd(&cnt[t], 1);  // early: overlaps gathers below
    int4 iv = *(const int4*)&inter[e * 4];
    int itarr[4] = {iv.x, iv.y, iv.z, iv.w};
    float4 sp = pos4[s];
    float4 tp = pos4[t];
    float4 ip0 = pos4[itarr[0]];
    float4 ip1 = pos4[itarr[1]];
    float4 ip2 = pos4[itarr[2]];
    float4 ip3 = pos4[itarr[3]];
    __syncthreads();  // Sb ready
    float dx = tp.x - sp.x, dy = tp.y - sp.y, dz = tp.z - sp.z;
    float dist1 = sqrtf(dx * dx + dy * dy + dz * dz);
    unsigned i1 = (unsigned)didx(Sb, dist1);
    float4 ips[4] = {ip0, ip1, ip2, ip3};
    unsigned w3 = 0, q20 = 0, q_0 = 0;
    #pragma unroll
    for (int hh = 0; hh < 4; ++hh) {
      float4 ip = ips[hh];
      float ax = tp.x - ip.x, ay = tp.y - ip.y, az = tp.z - ip.z;
      float dist2 = sqrtf(ax * ax + ay * ay + az * az);
      float bx = sp.x - ip.x, by = sp.y - ip.y, bz = sp.z - ip.z;
      float dist_ = sqrtf(bx * bx + by * by + bz * bz);
      unsigned idx2 = (unsigned)didx(Sb, dist2);
      unsigned idx_ = (unsigned)didx(Sb, dist_);
      if (hh == 0) { q20 = idx2; q_0 = idx_; }
      else w3 |= (idx2 | (idx_ << 5)) << ((hh - 1) * 10);
    }
    uint4 rec;
    rec.x = (unsigned)s | ((unsigned)itarr[0] << 16);
    rec.y = (unsigned)itarr[1] | ((unsigned)itarr[2] << 16);
    rec.z = (unsigned)itarr[3] | (i1 << 16) | (q20 << 21) | (q_0 << 26);
    rec.w = w3;
    if (p < SLOTS) ebuf[t * SLOTS + p] = rec;
    return;
  }
  // ---- gemm path: 16 rows x 512 cols, 4 waves (wave = 128-col slice) ----
  typedef __half Erow[EROW2];
  Erow* Esm = (Erow*)smem;  // [16][EROW2]
  int gi = bi - 12;
  int bx = gi % 625, half = gi / 625;  // half 0: cols 0..511; half 1: 512..1023
  int wv = tid >> 6, l = tid & 63;
  int m0 = bx * 16;  // 625*16 == N exactly
  int lm = l & 15, lk = (l >> 4) * 8;
  const float* fp = feat + (m0 + lm) * 128 + lk;
  const _Float16* bp = (const _Float16*)bigWT + lk + (half * 512 + wv * 128) * 128;
  half8 a[4];
  #pragma unroll
  for (int kt = 0; kt < 4; ++kt) {
    float4 u0 = *(const float4*)(fp + kt * 32);
    float4 u1 = *(const float4*)(fp + kt * 32 + 4);
    half8 t;
    t[0] = (_Float16)u0.x; t[1] = (_Float16)u0.y;
    t[2] = (_Float16)u0.z; t[3] = (_Float16)u0.w;
    t[4] = (_Float16)u1.x; t[5] = (_Float16)u1.y;
    t[6] = (_Float16)u1.z; t[7] = (_Float16)u1.w;
    a[kt] = t;
  }
  #pragma unroll
  for (int nt = 0; nt < 8; ++nt) {
    floatx4 acc = (floatx4){0.f, 0.f, 0.f, 0.f};
    #pragma unroll
    for (int kt = 0; kt < 4; ++kt) {
      half8 b = *(const half8*)(bp + (nt * 16 + lm) * 128 + kt * 32);
      acc = __builtin_amdgcn_mfma_f32_16x16x32_f16(a[kt], b, acc, 0, 0, 0);
    }
    int dd = wv * 128 + nt * 16 + lm;  // col within 512-block
    #pragma unroll
    for (int r4 = 0; r4 < 4; ++r4)
      Esm[(l >> 4) * 4 + r4][dd] = __float2half(acc[r4]);
  }
  __syncthreads();
  int r = tid >> 4, q = tid & 15;
  int m = m0 + r;
  if (half == 0) {
    // interleaved h|q1: slot g gets {h[g*4..+3], q1[g*4..+3]}
    #pragma unroll
    for (int u = 0; u < 4; ++u) {
      int g = q + u * 16;  // 0..63
      uint2 hp = *(const uint2*)&Esm[r][g * 4];
      uint2 qp = *(const uint2*)&Esm[r][256 + g * 4];
      uint4 v = make_uint4(hp.x, hp.y, qp.x, qp.y);
      *(uint4*)&qall[m * QREC + g * 8] = v;
    }
  } else {
    // q2|q3 head-major straight copy
    #pragma unroll
    for (int u = 0; u < 4; ++u) {
      int g2 = q + u * 16;  // uint4 index 0..63
      uint4 v = *(const uint4*)&Esm[r][g2 * 8];
      *(uint4*)&qall[m * QREC + 512 + g2 * 8] = v;
    }
  }
}

// ---------------------------------------------------------------------------
// D3: FUSED score + aggregation (unchanged from r11). Block per node, 4
// waves, TWO edges in flight. Wave-uniform ebuf loads; hr|q1 = ONE uint4
// gather. Head-major lanes; butterfly 16-lane sum; cross-head combine via
// 2 shfl_xor. Max-free softmax.
// ---------------------------------------------------------------------------
__device__ __forceinline__ float dpp_bfly_sum16(float v) {
  int x;
  // quad_perm [1,0,3,2] = xor1
  x = __builtin_amdgcn_update_dpp(0, __float_as_int(v), 0xB1, 0xf, 0xf, true);
  v += __int_as_float(x);
  // quad_perm [2,3,0,1] = xor2
  x = __builtin_amdgcn_update_dpp(0, __float_as_int(v), 0x4E, 0xf, 0xf, true);
  v += __int_as_float(x);
  // ROW_HALF_MIRROR: combine quads within 8
  x = __builtin_amdgcn_update_dpp(0, __float_as_int(v), 0x141, 0xf, 0xf, true);
  v += __int_as_float(x);
  // ROW_MIRROR: combine 8-halves within 16
  x = __builtin_amdgcn_update_dpp(0, __float_as_int(v), 0x140, 0xf, 0xf, true);
  v += __int_as_float(x);
  return v;
}

union H4u { uint2 u; __half2 h[2]; };
union H8u { uint4 u4; __half2 h2[4]; };

__device__ __forceinline__ float tanh_dot(H4u A, H4u B, H4u C, H4u X, H4u Y,
                                          H4u Z, float4 a4) {
  __half2 z0 = __hadd2(__hadd2(A.h[0], B.h[0]), __hadd2(C.h[0], X.h[0]));
  z0 = __hadd2(z0, __hadd2(Y.h[0], Z.h[0]));
  __half2 z1 = __hadd2(__hadd2(A.h[1], B.h[1]), __hadd2(C.h[1], X.h[1]));
  z1 = __hadd2(z1, __hadd2(Y.h[1], Z.h[1]));
  float2 f0 = __half22float2(z0);
  float2 f1 = __half22float2(z1);
  const float K = 2.885390082f;  // 2*log2(e)
  float p0 = __builtin_amdgcn_exp2f(f0.x * K);
  float p1 = __builtin_amdgcn_exp2f(f0.y * K);
  float p2 = __builtin_amdgcn_exp2f(f1.x * K);
  float p3 = __builtin_amdgcn_exp2f(f1.y * K);
  float r0 = __builtin_amdgcn_rcpf(p0 + 1.0f);
  float r1 = __builtin_amdgcn_rcpf(p1 + 1.0f);
  float r2 = __builtin_amdgcn_rcpf(p2 + 1.0f);
  float r3 = __builtin_amdgcn_rcpf(p3 + 1.0f);
  float dot = a4.x * r0;
  dot = fmaf(a4.y, r1, dot);
  dot = fmaf(a4.z, r2, dot);
  dot = fmaf(a4.w, r3, dot);
  float asum = (a4.x + a4.y) + (a4.z + a4.w);
  return fmaf(-2.0f, dot, asum);
}

__device__ __forceinline__ void dec_rec(uint4 r, int h, int* s, int* it,
                                        unsigned* i1, unsigned* q2,
                                        unsigned* q_) {
  *s = (int)(r.x & 0xffff);
  *it = (h == 0) ? (int)(r.x >> 16)
      : (h == 1) ? (int)(r.y & 0xffff)
      : (h == 2) ? (int)(r.y >> 16) : (int)(r.z & 0xffff);
  *i1 = (r.z >> 16) & 31;
  if (h == 0) {
    *q2 = (r.z >> 21) & 31;
    *q_ = (r.z >> 26) & 31;
  } else {
    unsigned f = r.w >> ((h - 1) * 10);
    *q2 = f & 31;
    *q_ = (f >> 5) & 31;
  }
}

__global__ __launch_bounds__(256) void score_agg_kernel(
    const int* __restrict__ cnt, const uint4* __restrict__ ebuf,
    const __half* __restrict__ qall, const __half* __restrict__ U16,
    const float* __restrict__ aout, float* __restrict__ out) {
  __shared__ float4 sm_num[4][64];
  __shared__ float sm_den[4][4];
  int tid = threadIdx.x;
  int w = tid >> 6, lane = tid & 63;
  int h = lane >> 4, c = lane & 15;
  int n = blockIdx.x;
  int deg = cnt[n];
  if (deg > SLOTS) deg = SLOTS;
  H4u C;
  C.u = *(const uint2*)(qall + n * QREC + 768 + h * 64 + c * 4);
  const float4 a4 = *((const float4*)(aout + h * 64) + c);
  float4 num = make_float4(0.f, 0.f, 0.f, 0.f);
  float den = 0.f;
  int hc4 = h * 64 + c * 4;
  int g8 = hc4 * 2;  // (h*16+c)*8
  const uint4* eb = ebuf + n * SLOTS;
  for (int i = w; i < deg; i += 8) {
    int iB = i + 4;
    int vB = (iB < deg);       // wave-uniform
    uint4 rA = eb[i];          // uniform address -> broadcast/scalar load
    uint4 rB = eb[vB ? iB : i];
    int sA, itA, sB, itB;
    unsigned i1A, q2A, q_A, i1B, q2B, q_B;
    dec_rec(rA, h, &sA, &itA, &i1A, &q2A, &q_A);
    dec_rec(rB, h, &sB, &itB, &i1B, &q2B, &q_B);
    H8u AH0, AH1;
    H4u B0, X0, Y0, Z0, B1, X1, Y1, Z1;
    AH0.u4 = *(const uint4*)(qall + sA * QREC + g8);
    B0.u = *(const uint2*)(qall + itA * QREC + 512 + hc4);
    X0.u = *(const uint2*)(U16 + (h * 32 + (int)i1A) * 64 + c * 4);
    Y0.u = *(const uint2*)(U16 + 8192 + (h * 32 + (int)q2A) * 64 + c * 4);
    Z0.u = *(const uint2*)(U16 + 16384 + (h * 32 + (int)q_A) * 64 + c * 4);
    AH1.u4 = *(const uint4*)(qall + sB * QREC + g8);
    B1.u = *(const uint2*)(qall + itB * QREC + 512 + hc4);
    X1.u = *(const uint2*)(U16 + (h * 32 + (int)i1B) * 64 + c * 4);
    Y1.u = *(const uint2*)(U16 + 8192 + (h * 32 + (int)q2B) * 64 + c * 4);
    Z1.u = *(const uint2*)(U16 + 16384 + (h * 32 + (int)q_B) * 64 + c * 4);
    H4u A0, A1;
    A0.h[0] = AH0.h2[2]; A0.h[1] = AH0.h2[3];
    A1.h[0] = AH1.h2[2]; A1.h[1] = AH1.h2[3];
    float v0 = tanh_dot(A0, B0, C, X0, Y0, Z0, a4);
    float v1 = tanh_dot(A1, B1, C, X1, Y1, Z1, a4);
    v0 = dpp_bfly_sum16(v0);
    v1 = dpp_bfly_sum16(v1);
    float ex0 = __expf(v0);
    float ex1 = vB ? __expf(v1) : 0.f;
    float2 h00 = __half22float2(AH0.h2[0]);
    float2 h01 = __half22float2(AH0.h2[1]);
    float2 h10 = __half22float2(AH1.h2[0]);
    float2 h11 = __half22float2(AH1.h2[1]);
    num.x += ex0 * h00.x + ex1 * h10.x;
    num.y += ex0 * h00.y + ex1 * h10.y;
    num.z += ex0 * h01.x + ex1 * h11.x;
    num.w += ex0 * h01.y + ex1 * h11.y;
    den += ex0 + ex1;
  }
  sm_num[w][lane] = num;
  if (c == 0) sm_den[w][h] = den;
  __syncthreads();
  if (tid < 64) {
    float4 n0 = sm_num[0][lane], n1 = sm_num[1][lane];
    float4 n2 = sm_num[2][lane], n3 = sm_num[3][lane];
    float dt = sm_den[0][h] + sm_den[1][h] + sm_den[2][h] + sm_den[3][h];
    float4 t = make_float4(0.f, 0.f, 0.f, 0.f);
    if (deg > 0) {
      float inv = 1.0f / dt;
      t.x = (n0.x + n1.x + n2.x + n3.x) * inv;
      t.y = (n0.y + n1.y + n2.y + n3.y) * inv;
      t.z = (n0.z + n1.z + n2.z + n3.z) * inv;
      t.w = (n0.w + n1.w + n2.w + n3.w) * inv;
    }
    // combine across the 4 head groups (lanes differing in bits 4,5)
    t.x += __shfl_xor(t.x, 16); t.y += __shfl_xor(t.y, 16);
    t.z += __shfl_xor(t.z, 16); t.w += __shfl_xor(t.w, 16);
    t.x += __shfl_xor(t.x, 32); t.y += __shfl_xor(t.y, 32);
    t.z += __shfl_xor(t.z, 32); t.w += __shfl_xor(t.w, 32);
    if (h == 0) {
      t.x *= 0.25f; t.y *= 0.25f; t.z *= 0.25f; t.w *= 0.25f;
      *(float4*)&out[n * 64 + c * 4] = t;
    }
  }
}

// ---------------------------------------------------------------------------
extern "C" void kernel_launch(void* const* d_in, const int* in_sizes, int n_in,
                              void* d_out, int out_size, void* d_ws,
                              size_t ws_size, hipStream_t stream) {
  const float* feat = (const float*)d_in[0];
  const float* loc = (const float*)d_in[1];
  const int* src = (const int*)d_in[2];
  const int* dst = (const int*)d_in[3];
  const int* inter = (const int*)d_in[4];
  const float* Wfc = (const float*)d_in[5];
  const float* emb = (const float*)d_in[6];
  const float* G = (const float*)d_in[7];
  const float* fc1 = (const float*)d_in[8];
  const float* fc2 = (const float*)d_in[9];
  const float* fc3 = (const float*)d_in[10];
  const float* fcc = (const float*)d_in[11];
  const float* aout = (const float*)d_in[12];
  const float* bnd = (const float*)d_in[13];
  float* out = (float*)d_out;

  __half* qall = (__half*)d_ws;           // N*1024 halfs (20.48 MB)
  __half* bigWT = qall + N_NODES * QREC;  // 1024*128 halfs
  __half* U16 = bigWT + 1024 * 128;       // 3*4*2048 halfs
  uint4* ebuf = (uint4*)(U16 + 3 * H * 2048);  // N*SLOTS uint4 (10.24 MB)
  int* cnt = (int*)(ebuf + N_NODES * SLOTS);   // N ints
  float4* pos4 = (float4*)(cnt + N_NODES);     // N float4 (160 KB)

  prep_kernel<<<44, 512, 0, stream>>>(fc1, fc2, fc3, fcc, Wfc, loc, bigWT,
                                      cnt, pos4);
  fused_kernel<<<1887, 256, 0, stream>>>(feat, bigWT, qall, pos4, src, dst,
                                         inter, bnd, cnt, ebuf, fc1, fc2, fc3,
                                         fcc, G, emb, U16);
  score_agg_kernel<<<N_NODES, 256, 0, stream>>>(cnt, ebuf, qall, U16, aout,
                                                out);
}

// Round 13
// 171.983 us; speedup vs baseline: 1.0475x; 1.0475x over previous
//
#include <hip/hip_runtime.h>
#include <hip/hip_fp16.h>
#include <math.h>

#define N_NODES 10000
#define E_EDGES 160000
#define DMODEL 64
#define H 4
#define NBOUND 31
#define SLOTS 64  // fixed per-node CSR bucket; P(deg>64)<1e-11 for multinomial(16)
// qall record per node (fp16, 1024 halves):
//  [0:512)    interleaved h|q1 per lane-slot g = head*16+c (g in [0,64)):
//             halves g*8+0..3 = h[head][c*4..+3]
//             halves g*8+4..7 = q1[head][c*4..+3]
//             -> score+agg src-row gather is ONE uint4 per lane
//  [512:768)  q2: 512 + head*64 + d   (head-major)
//  [768:1024) q3: 768 + head*64 + d
#define QREC 1024

typedef _Float16 half8 __attribute__((ext_vector_type(8)));
typedef float floatx4 __attribute__((ext_vector_type(4)));

// ---------------------------------------------------------------------------
// LDS 64-wide microtile helper: o[r] = sum_t A[i0+r][t] * B[t][j].
// ---------------------------------------------------------------------------
__device__ __forceinline__ void mm4(const float* __restrict__ S, int aoff,
                                    int astride, int boff, int i0, int j,
                                    int Kdim, float o[4]) {
  float a0 = 0.f, a1 = 0.f, a2 = 0.f, a3 = 0.f;
  for (int t4 = 0; t4 < (Kdim >> 2); ++t4) {
    float4 f0 = *(const float4*)&S[aoff + (i0 + 0) * astride + t4 * 4];
    float4 f1 = *(const float4*)&S[aoff + (i0 + 1) * astride + t4 * 4];
    float4 f2 = *(const float4*)&S[aoff + (i0 + 2) * astride + t4 * 4];
    float4 f3 = *(const float4*)&S[aoff + (i0 + 3) * astride + t4 * 4];
    float b0 = S[boff + (t4 * 4 + 0) * 64 + j];
    float b1 = S[boff + (t4 * 4 + 1) * 64 + j];
    float b2 = S[boff + (t4 * 4 + 2) * 64 + j];
    float b3 = S[boff + (t4 * 4 + 3) * 64 + j];
    a0 += f0.x * b0 + f0.y * b1 + f0.z * b2 + f0.w * b3;
    a1 += f1.x * b0 + f1.y * b1 + f1.z * b2 + f1.w * b3;
    a2 += f2.x * b0 + f2.y * b1 + f2.z * b2 + f2.w * b3;
    a3 += f3.x * b0 + f3.y * b1 + f3.z * b2 + f3.w * b3;
  }
  o[0] = a0; o[1] = a1; o[2] = a2; o[3] = a3;
}

__device__ __forceinline__ int didx(const float* __restrict__ bnd2, float d) {
  int g = (int)(d * 10.0f);
  g = (g < 0) ? 0 : ((g > 31) ? 31 : g);
  g += (bnd2[g + 1] < d) ? 1 : 0;
  g -= (bnd2[g] >= d) ? 1 : 0;
  return g;
}

// ---------------------------------------------------------------------------
// D1: prep (r9 proven form). Three independent chains per (k,h), all
// LDS-staged (no global-A matmuls -- r12 lesson):
//   blocks  0..11 chain A0: B1 = fckU@F -> WC0 (+ raw WfcT upper, k==0)
//   blocks 12..23 chain A1: B1 = fckU@F -> WC1 (+ raw WfcT lower, k==0)
//   blocks 24..35 chain B : B2 = fckL@F -> GB -> U -> U16
//   blocks 36..55: zero cnt + build pos4 table.
// ---------------------------------------------------------------------------
__global__ __launch_bounds__(512) void prep_kernel(
    const float* __restrict__ fc1, const float* __restrict__ fc2,
    const float* __restrict__ fc3, const float* __restrict__ fcc,
    const float* __restrict__ Wfc, const float* __restrict__ G,
    const float* __restrict__ emb, const float* __restrict__ pos,
    __half* __restrict__ bigWT, __half* __restrict__ U16,
    int* __restrict__ cnt, float4* __restrict__ pos4) {
  __shared__ __align__(16) float S[12288];
  int bi = blockIdx.x;
  int tid = threadIdx.x;
  if (bi >= 36) {
    int n = (bi - 36) * 512 + tid;
    if (n < N_NODES) {
      cnt[n] = 0;
      pos4[n] = make_float4(pos[n * 3], pos[n * 3 + 1], pos[n * 3 + 2], 0.f);
    }
    return;
  }
  int ca = bi / 12;  // 0 = A0, 1 = A1, 2 = B
  int kh = bi % 12;
  int k = kh >> 2, h = kh & 3;
  const float* fck = (k == 0) ? fc1 : (k == 1) ? fc2 : fc3;
  fck += h * 128 * 64;
  const float* F = fcc + h * 192 * 64 + k * 64 * 64;
  int j = tid & 63, ig = tid >> 6;  // ig 0..7
  float o[4];
  if (ca < 2) {
    // ======== chain A0/A1: B1 -> WC{0,1} ========
    #pragma unroll
    for (int u = 0; u < 2; ++u) {
      ((float4*)S)[u * 512 + tid] = ((const float4*)F)[u * 512 + tid];
      ((float4*)(S + 4096))[u * 512 + tid] = ((const float4*)fck)[u * 512 + tid];
    }
    __syncthreads();
    // B1 = fckU @ F -> S[8192)
    #pragma unroll
    for (int rg = 0; rg < 2; ++rg) {
      int i0 = ig * 8 + rg * 4;
      mm4(S, 4096, 64, 0, i0, j, 64, o);
      S[8192 + (i0 + 0) * 64 + j] = o[0];
      S[8192 + (i0 + 1) * 64 + j] = o[1];
      S[8192 + (i0 + 2) * 64 + j] = o[2];
      S[8192 + (i0 + 3) * 64 + j] = o[3];
    }
    __syncthreads();
    // stage Wfc rows (A0: 0..63, A1: 64..127), col slice h -> S[4096)
    int rbase = (ca == 0) ? 0 : 64;
    #pragma unroll
    for (int u = 0; u < 2; ++u) {
      int fi = u * 512 + tid;
      int i = fi >> 4, c4 = fi & 15;
      ((float4*)(S + 4096))[fi] =
          ((const float4*)(Wfc + (rbase + i) * 256 + h * 64))[c4];
    }
    __syncthreads();
    if (k == 0) {
      #pragma unroll
      for (int u = 0; u < 8; ++u) {
        int idx = u * 512 + tid;
        int i = idx >> 6, jj = idx & 63;
        bigWT[(h * 64 + jj) * 128 + rbase + i] = __float2half(S[4096 + idx]);
      }
    }
    // WC = Wfc-half @ B1 -> bigWT cols rbase..rbase+63
    #pragma unroll
    for (int rg = 0; rg < 2; ++rg) {
      int i0 = ig * 8 + rg * 4;
      mm4(S, 4096, 64, 8192, i0, j, 64, o);
      int rb = ((k + 1) * 256 + h * 64 + j) * 128 + rbase;
      bigWT[rb + i0 + 0] = __float2half(o[0]);
      bigWT[rb + i0 + 1] = __float2half(o[1]);
      bigWT[rb + i0 + 2] = __float2half(o[2]);
      bigWT[rb + i0 + 3] = __float2half(o[3]);
    }
    return;
  }
  // ======== chain B: B2 -> GB -> U ========
  #pragma unroll
  for (int u = 0; u < 2; ++u) {
    ((float4*)S)[u * 512 + tid] = ((const float4*)F)[u * 512 + tid];
    ((float4*)(S + 4096))[u * 512 + tid] =
        ((const float4*)(fck + 4096))[u * 512 + tid];
  }
  __syncthreads();
  // B2 = fckL @ F -> S[8192)
  #pragma unroll
  for (int rg = 0; rg < 2; ++rg) {
    int i0 = ig * 8 + rg * 4;
    mm4(S, 4096, 64, 0, i0, j, 64, o);
    S[8192 + (i0 + 0) * 64 + j] = o[0];
    S[8192 + (i0 + 1) * 64 + j] = o[1];
    S[8192 + (i0 + 2) * 64 + j] = o[2];
    S[8192 + (i0 + 3) * 64 + j] = o[3];
  }
  __syncthreads();
  // stage G_h -> S[0:2048), emb -> S[2048:3072)
  ((float4*)S)[tid] = ((const float4*)(G + h * 2048))[tid];
  if (tid < 256) ((float4*)(S + 2048))[tid] = ((const float4*)emb)[tid];
  __syncthreads();
  // GB = G @ B2 (32x64) -> S[3072)
  {
    int i0 = ig * 4;  // 8 igs x 4 rows = 32
    mm4(S, 0, 64, 8192, i0, j, 64, o);
    S[3072 + (i0 + 0) * 64 + j] = o[0];
    S[3072 + (i0 + 1) * 64 + j] = o[1];
    S[3072 + (i0 + 2) * 64 + j] = o[2];
    S[3072 + (i0 + 3) * 64 + j] = o[3];
  }
  __syncthreads();
  // U = emb @ GB (32x64, K=32) -> U16
  {
    int i0 = ig * 4;
    mm4(S, 2048, 32, 3072, i0, j, 32, o);
    int base = k * 8192 + h * 2048;
    U16[base + (i0 + 0) * 64 + j] = __float2half(o[0]);
    U16[base + (i0 + 1) * 64 + j] = __float2half(o[1]);
    U16[base + (i0 + 2) * 64 + j] = __float2half(o[2]);
    U16[base + (i0 + 3) * 64 + j] = __float2half(o[3]);
  }
}

// ---------------------------------------------------------------------------
// D2: FUSED gemm + edge ONLY (chainB evicted to prep -- r12 lesson). LDS =
// 16.6 KB (Esm), VGPR ~60 -> 8 blocks/CU; the whole 1875-block grid is
// co-resident. Clean test of the occupancy hypothesis for the ~46 us wall.
//   blocks 0..1249    = MFMA gemm: 16 rows x 512 cols (625 per half).
//                       half 0 (h|q1) -> interleaved qall[0:512); half 1
//                       (q2|q3) head-major. N = 625*16 exactly.
//   blocks 1250..1874 = edge pass (pos4 gathers, early atomic, CSR scatter)
// record uint4: x = s | it0<<16 ; y = it1 | it2<<16 ;
//               z = it3 | i1<<16 | q2_0<<21 | q__0<<26 ;
//               w = (q2_h | q__h<<5) << ((h-1)*10)  for h=1..3
// ---------------------------------------------------------------------------
#define EROW2 520  // epilogue LDS row stride in halves
#define SMEM_BYTES 16640  // Esm 16x520x2 = 16640; Sb = 192

__global__ __launch_bounds__(256) void gemm_edge_kernel(
    const float* __restrict__ feat, const __half* __restrict__ bigWT,
    __half* __restrict__ qall, const float4* __restrict__ pos4,
    const int* __restrict__ src, const int* __restrict__ dst,
    const int* __restrict__ inter, const float* __restrict__ boundaries,
    int* __restrict__ cnt, uint4* __restrict__ ebuf) {
  __shared__ __align__(16) char smem[SMEM_BYTES];
  int bi = blockIdx.x;
  int tid = threadIdx.x;
  if (bi >= 1250) {
    // ---- edge path ----
    float* Sb = (float*)smem;
    if (tid < NBOUND) Sb[tid + 1] = boundaries[tid];
    if (tid == NBOUND) { Sb[0] = -INFINITY; Sb[32] = INFINITY; }
    int e = (bi - 1250) * 256 + tid;  // 625*256 == E exactly
    int s = src[e], t = dst[e];
    int p = atomicAdd(&cnt[t], 1);  // early: overlaps gathers below
    int4 iv = *(const int4*)&inter[e * 4];
    int itarr[4] = {iv.x, iv.y, iv.z, iv.w};
    float4 sp = pos4[s];
    float4 tp = pos4[t];
    float4 ip0 = pos4[itarr[0]];
    float4 ip1 = pos4[itarr[1]];
    float4 ip2 = pos4[itarr[2]];
    float4 ip3 = pos4[itarr[3]];
    __syncthreads();  // Sb ready
    float dx = tp.x - sp.x, dy = tp.y - sp.y, dz = tp.z - sp.z;
    float dist1 = sqrtf(dx * dx + dy * dy + dz * dz);
    unsigned i1 = (unsigned)didx(Sb, dist1);
    float4 ips[4] = {ip0, ip1, ip2, ip3};
    unsigned w3 = 0, q20 = 0, q_0 = 0;
    #pragma unroll
    for (int hh = 0; hh < 4; ++hh) {
      float4 ip = ips[hh];
      float ax = tp.x - ip.x, ay = tp.y - ip.y, az = tp.z - ip.z;
      float dist2 = sqrtf(ax * ax + ay * ay + az * az);
      float bx = sp.x - ip.x, by = sp.y - ip.y, bz = sp.z - ip.z;
      float dist_ = sqrtf(bx * bx + by * by + bz * bz);
      unsigned idx2 = (unsigned)didx(Sb, dist2);
      unsigned idx_ = (unsigned)didx(Sb, dist_);
      if (hh == 0) { q20 = idx2; q_0 = idx_; }
      else w3 |= (idx2 | (idx_ << 5)) << ((hh - 1) * 10);
    }
    uint4 rec;
    rec.x = (unsigned)s | ((unsigned)itarr[0] << 16);
    rec.y = (unsigned)itarr[1] | ((unsigned)itarr[2] << 16);
    rec.z = (unsigned)itarr[3] | (i1 << 16) | (q20 << 21) | (q_0 << 26);
    rec.w = w3;
    if (p < SLOTS) ebuf[t * SLOTS + p] = rec;
    return;
  }
  // ---- gemm path: 16 rows x 512 cols, 4 waves (wave = 128-col slice) ----
  typedef __half Erow[EROW2];
  Erow* Esm = (Erow*)smem;  // [16][EROW2]
  int bx = bi % 625, half = bi / 625;  // half 0: cols 0..511; half 1: 512..1023
  int wv = tid >> 6, l = tid & 63;
  int m0 = bx * 16;  // 625*16 == N exactly
  int lm = l & 15, lk = (l >> 4) * 8;
  const float* fp = feat + (m0 + lm) * 128 + lk;
  const _Float16* bp = (const _Float16*)bigWT + lk + (half * 512 + wv * 128) * 128;
  half8 a[4];
  #pragma unroll
  for (int kt = 0; kt < 4; ++kt) {
    float4 u0 = *(const float4*)(fp + kt * 32);
    float4 u1 = *(const float4*)(fp + kt * 32 + 4);
    half8 t;
    t[0] = (_Float16)u0.x; t[1] = (_Float16)u0.y;
    t[2] = (_Float16)u0.z; t[3] = (_Float16)u0.w;
    t[4] = (_Float16)u1.x; t[5] = (_Float16)u1.y;
    t[6] = (_Float16)u1.z; t[7] = (_Float16)u1.w;
    a[kt] = t;
  }
  #pragma unroll
  for (int nt = 0; nt < 8; ++nt) {
    floatx4 acc = (floatx4){0.f, 0.f, 0.f, 0.f};
    #pragma unroll
    for (int kt = 0; kt < 4; ++kt) {
      half8 b = *(const half8*)(bp + (nt * 16 + lm) * 128 + kt * 32);
      acc = __builtin_amdgcn_mfma_f32_16x16x32_f16(a[kt], b, acc, 0, 0, 0);
    }
    int dd = wv * 128 + nt * 16 + lm;  // col within 512-block
    #pragma unroll
    for (int r4 = 0; r4 < 4; ++r4)
      Esm[(l >> 4) * 4 + r4][dd] = __float2half(acc[r4]);
  }
  __syncthreads();
  int r = tid >> 4, q = tid & 15;
  int m = m0 + r;
  if (half == 0) {
    // interleaved h|q1: slot g gets {h[g*4..+3], q1[g*4..+3]}
    #pragma unroll
    for (int u = 0; u < 4; ++u) {
      int g = q + u * 16;  // 0..63
      uint2 hp = *(const uint2*)&Esm[r][g * 4];
      uint2 qp = *(const uint2*)&Esm[r][256 + g * 4];
      uint4 v = make_uint4(hp.x, hp.y, qp.x, qp.y);
      *(uint4*)&qall[m * QREC + g * 8] = v;
    }
  } else {
    // q2|q3 head-major straight copy
    #pragma unroll
    for (int u = 0; u < 4; ++u) {
      int g2 = q + u * 16;  // uint4 index 0..63
      uint4 v = *(const uint4*)&Esm[r][g2 * 8];
      *(uint4*)&qall[m * QREC + 512 + g2 * 8] = v;
    }
  }
}

// ---------------------------------------------------------------------------
// D3: FUSED score + aggregation (unchanged from r11). Block per node, 4
// waves, TWO edges in flight. Wave-uniform ebuf loads; hr|q1 = ONE uint4
// gather. Head-major lanes; butterfly 16-lane sum; cross-head combine via
// 2 shfl_xor. Max-free softmax.
// ---------------------------------------------------------------------------
__device__ __forceinline__ float dpp_bfly_sum16(float v) {
  int x;
  // quad_perm [1,0,3,2] = xor1
  x = __builtin_amdgcn_update_dpp(0, __float_as_int(v), 0xB1, 0xf, 0xf, true);
  v += __int_as_float(x);
  // quad_perm [2,3,0,1] = xor2
  x = __builtin_amdgcn_update_dpp(0, __float_as_int(v), 0x4E, 0xf, 0xf, true);
  v += __int_as_float(x);
  // ROW_HALF_MIRROR: combine quads within 8
  x = __builtin_amdgcn_update_dpp(0, __float_as_int(v), 0x141, 0xf, 0xf, true);
  v += __int_as_float(x);
  // ROW_MIRROR: combine 8-halves within 16
  x = __builtin_amdgcn_update_dpp(0, __float_as_int(v), 0x140, 0xf, 0xf, true);
  v += __int_as_float(x);
  return v;
}

union H4u { uint2 u; __half2 h[2]; };
union H8u { uint4 u4; __half2 h2[4]; };

__device__ __forceinline__ float tanh_dot(H4u A, H4u B, H4u C, H4u X, H4u Y,
                                          H4u Z, float4 a4) {
  __half2 z0 = __hadd2(__hadd2(A.h[0], B.h[0]), __hadd2(C.h[0], X.h[0]));
  z0 = __hadd2(z0, __hadd2(Y.h[0], Z.h[0]));
  __half2 z1 = __hadd2(__hadd2(A.h[1], B.h[1]), __hadd2(C.h[1], X.h[1]));
  z1 = __hadd2(z1, __hadd2(Y.h[1], Z.h[1]));
  float2 f0 = __half22float2(z0);
  float2 f1 = __half22float2(z1);
  const float K = 2.885390082f;  // 2*log2(e)
  float p0 = __builtin_amdgcn_exp2f(f0.x * K);
  float p1 = __builtin_amdgcn_exp2f(f0.y * K);
  float p2 = __builtin_amdgcn_exp2f(f1.x * K);
  float p3 = __builtin_amdgcn_exp2f(f1.y * K);
  float r0 = __builtin_amdgcn_rcpf(p0 + 1.0f);
  float r1 = __builtin_amdgcn_rcpf(p1 + 1.0f);
  float r2 = __builtin_amdgcn_rcpf(p2 + 1.0f);
  float r3 = __builtin_amdgcn_rcpf(p3 + 1.0f);
  float dot = a4.x * r0;
  dot = fmaf(a4.y, r1, dot);
  dot = fmaf(a4.z, r2, dot);
  dot = fmaf(a4.w, r3, dot);
  float asum = (a4.x + a4.y) + (a4.z + a4.w);
  return fmaf(-2.0f, dot, asum);
}

__device__ __forceinline__ void dec_rec(uint4 r, int h, int* s, int* it,
                                        unsigned* i1, unsigned* q2,
                                        unsigned* q_) {
  *s = (int)(r.x & 0xffff);
  *it = (h == 0) ? (int)(r.x >> 16)
      : (h == 1) ? (int)(r.y & 0xffff)
      : (h == 2) ? (int)(r.y >> 16) : (int)(r.z & 0xffff);
  *i1 = (r.z >> 16) & 31;
  if (h == 0) {
    *q2 = (r.z >> 21) & 31;
    *q_ = (r.z >> 26) & 31;
  } else {
    unsigned f = r.w >> ((h - 1) * 10);
    *q2 = f & 31;
    *q_ = (f >> 5) & 31;
  }
}

__global__ __launch_bounds__(256) void score_agg_kernel(
    const int* __restrict__ cnt, const uint4* __restrict__ ebuf,
    const __half* __restrict__ qall, const __half* __restrict__ U16,
    const float* __restrict__ aout, float* __restrict__ out) {
  __shared__ float4 sm_num[4][64];
  __shared__ float sm_den[4][4];
  int tid = threadIdx.x;
  int w = tid >> 6, lane = tid & 63;
  int h = lane >> 4, c = lane & 15;
  int n = blockIdx.x;
  int deg = cnt[n];
  if (deg > SLOTS) deg = SLOTS;
  H4u C;
  C.u = *(const uint2*)(qall + n * QREC + 768 + h * 64 + c * 4);
  const float4 a4 = *((const float4*)(aout + h * 64) + c);
  float4 num = make_float4(0.f, 0.f, 0.f, 0.f);
  float den = 0.f;
  int hc4 = h * 64 + c * 4;
  int g8 = hc4 * 2;  // (h*16+c)*8
  const uint4* eb = ebuf + n * SLOTS;
  for (int i = w; i < deg; i += 8) {
    int iB = i + 4;
    int vB = (iB < deg);       // wave-uniform
    uint4 rA = eb[i];          // uniform address -> broadcast/scalar load
    uint4 rB = eb[vB ? iB : i];
    int sA, itA, sB, itB;
    unsigned i1A, q2A, q_A, i1B, q2B, q_B;
    dec_rec(rA, h, &sA, &itA, &i1A, &q2A, &q_A);
    dec_rec(rB, h, &sB, &itB, &i1B, &q2B, &q_B);
    H8u AH0, AH1;
    H4u B0, X0, Y0, Z0, B1, X1, Y1, Z1;
    AH0.u4 = *(const uint4*)(qall + sA * QREC + g8);
    B0.u = *(const uint2*)(qall + itA * QREC + 512 + hc4);
    X0.u = *(const uint2*)(U16 + (h * 32 + (int)i1A) * 64 + c * 4);
    Y0.u = *(const uint2*)(U16 + 8192 + (h * 32 + (int)q2A) * 64 + c * 4);
    Z0.u = *(const uint2*)(U16 + 16384 + (h * 32 + (int)q_A) * 64 + c * 4);
    AH1.u4 = *(const uint4*)(qall + sB * QREC + g8);
    B1.u = *(const uint2*)(qall + itB * QREC + 512 + hc4);
    X1.u = *(const uint2*)(U16 + (h * 32 + (int)i1B) * 64 + c * 4);
    Y1.u = *(const uint2*)(U16 + 8192 + (h * 32 + (int)q2B) * 64 + c * 4);
    Z1.u = *(const uint2*)(U16 + 16384 + (h * 32 + (int)q_B) * 64 + c * 4);
    H4u A0, A1;
    A0.h[0] = AH0.h2[2]; A0.h[1] = AH0.h2[3];
    A1.h[0] = AH1.h2[2]; A1.h[1] = AH1.h2[3];
    float v0 = tanh_dot(A0, B0, C, X0, Y0, Z0, a4);
    float v1 = tanh_dot(A1, B1, C, X1, Y1, Z1, a4);
    v0 = dpp_bfly_sum16(v0);
    v1 = dpp_bfly_sum16(v1);
    float ex0 = __expf(v0);
    float ex1 = vB ? __expf(v1) : 0.f;
    float2 h00 = __half22float2(AH0.h2[0]);
    float2 h01 = __half22float2(AH0.h2[1]);
    float2 h10 = __half22float2(AH1.h2[0]);
    float2 h11 = __half22float2(AH1.h2[1]);
    num.x += ex0 * h00.x + ex1 * h10.x;
    num.y += ex0 * h00.y + ex1 * h10.y;
    num.z += ex0 * h01.x + ex1 * h11.x;
    num.w += ex0 * h01.y + ex1 * h11.y;
    den += ex0 + ex1;
  }
  sm_num[w][lane] = num;
  if (c == 0) sm_den[w][h] = den;
  __syncthreads();
  if (tid < 64) {
    float4 n0 = sm_num[0][lane], n1 = sm_num[1][lane];
    float4 n2 = sm_num[2][lane], n3 = sm_num[3][lane];
    float dt = sm_den[0][h] + sm_den[1][h] + sm_den[2][h] + sm_den[3][h];
    float4 t = make_float4(0.f, 0.f, 0.f, 0.f);
    if (deg > 0) {
      float inv = 1.0f / dt;
      t.x = (n0.x + n1.x + n2.x + n3.x) * inv;
      t.y = (n0.y + n1.y + n2.y + n3.y) * inv;
      t.z = (n0.z + n1.z + n2.z + n3.z) * inv;
      t.w = (n0.w + n1.w + n2.w + n3.w) * inv;
    }
    // combine across the 4 head groups (lanes differing in bits 4,5)
    t.x += __shfl_xor(t.x, 16); t.y += __shfl_xor(t.y, 16);
    t.z += __shfl_xor(t.z, 16); t.w += __shfl_xor(t.w, 16);
    t.x += __shfl_xor(t.x, 32); t.y += __shfl_xor(t.y, 32);
    t.z += __shfl_xor(t.z, 32); t.w += __shfl_xor(t.w, 32);
    if (h == 0) {
      t.x *= 0.25f; t.y *= 0.25f; t.z *= 0.25f; t.w *= 0.25f;
      *(float4*)&out[n * 64 + c * 4] = t;
    }
  }
}

// ---------------------------------------------------------------------------
extern "C" void kernel_launch(void* const* d_in, const int* in_sizes, int n_in,
                              void* d_out, int out_size, void* d_ws,
                              size_t ws_size, hipStream_t stream) {
  const float* feat = (const float*)d_in[0];
  const float* loc = (const float*)d_in[1];
  const int* src = (const int*)d_in[2];
  const int* dst = (const int*)d_in[3];
  const int* inter = (const int*)d_in[4];
  const float* Wfc = (const float*)d_in[5];
  const float* emb = (const float*)d_in[6];
  const float* G = (const float*)d_in[7];
  const float* fc1 = (const float*)d_in[8];
  const float* fc2 = (const float*)d_in[9];
  const float* fc3 = (const float*)d_in[10];
  const float* fcc = (const float*)d_in[11];
  const float* aout = (const float*)d_in[12];
  const float* bnd = (const float*)d_in[13];
  float* out = (float*)d_out;

  __half* qall = (__half*)d_ws;           // N*1024 halfs (20.48 MB)
  __half* bigWT = qall + N_NODES * QREC;  // 1024*128 halfs
  __half* U16 = bigWT + 1024 * 128;       // 3*4*2048 halfs
  uint4* ebuf = (uint4*)(U16 + 3 * H * 2048);  // N*SLOTS uint4 (10.24 MB)
  int* cnt = (int*)(ebuf + N_NODES * SLOTS);   // N ints
  float4* pos4 = (float4*)(cnt + N_NODES);     // N float4 (160 KB)

  prep_kernel<<<56, 512, 0, stream>>>(fc1, fc2, fc3, fcc, Wfc, G, emb, loc,
                                      bigWT, U16, cnt, pos4);
  gemm_edge_kernel<<<1875, 256, 0, stream>>>(feat, bigWT, qall, pos4, src,
                                             dst, inter, bnd, cnt, ebuf);
  score_agg_kernel<<<N_NODES, 256, 0, stream>>>(cnt, ebuf, qall, U16, aout,
                                                out);
}